// Round 9
// baseline (728.019 us; speedup 1.0000x reference)
//
#include <hip/hip_runtime.h>
#include <hip/hip_bf16.h>

#define NN   50000
#define NE   800000
#define MP   3
#define DIN  128
#define DF   256     // HEADS*OUT_DIM
#define NH   8
#define HID  128
#define NC   (MP*NN)              // 150000
#define SCAN_NB ((NC + 255)/256)  // 586

typedef unsigned short u16;
typedef unsigned int   u32;
typedef __attribute__((ext_vector_type(8))) short bf16x8;   // MFMA A/B frag
typedef __attribute__((ext_vector_type(4))) float f32x4;    // MFMA C/D frag
typedef __attribute__((ext_vector_type(2))) float f32x2;    // pk-math pair

__device__ __forceinline__ float bf2f(u16 u) {
    return __uint_as_float(((u32)u) << 16);
}
__device__ __forceinline__ u16 f2bf(float f) {
    u32 x = __float_as_uint(f);
    u32 r = x + 0x7fffu + ((x >> 16) & 1u);   // round-to-nearest-even
    return (u16)(r >> 16);
}
__device__ __forceinline__ f32x2 bfp(u32 u) {   // unpack bf16 pair -> f32x2
    f32x2 r;
    r.x = __uint_as_float(u << 16);
    r.y = __uint_as_float(u & 0xffff0000u);
    return r;
}
__device__ __forceinline__ float tanh_fast(float x) {
    float c = fminf(fmaxf(x, -15.f), 15.f);
    float t = __expf(2.f * c);
    return (t - 1.f) / (t + 1.f);
}

// ---------------------------------------------------------------------------
// 0) merged one-time converts: h->hb, Wg->WgT (M,DF,DIN), W1->W1T (HID,DF),
//    WAL = Wg @ blockdiag(al|ar) -> WALT[m][c][k] (c: 0..7 el, 8..15 er).
// ---------------------------------------------------------------------------
#define CVT_H_N   (NN * DIN / 8)          // 800000
#define CVT_WG_N  (MP * DF * DIN)         // 98304
#define CVT_W1_N  (HID * DF)              // 32768
#define CVT_WAL_N (MP * 16 * DIN)         // 6144
__global__ __launch_bounds__(256) void k_cvt_all(
    const float* __restrict__ h, const float* __restrict__ Wg, const float* __restrict__ W1,
    const float* __restrict__ al, const float* __restrict__ ar,
    u16* __restrict__ hb, u16* __restrict__ WgT, u16* __restrict__ W1T, u16* __restrict__ WALT)
{
    int gid = blockIdx.x * 256 + threadIdx.x;
    if (gid < CVT_H_N) {
        size_t i8 = (size_t)gid * 8;
        float4 a = *(const float4*)(h + i8);
        float4 b = *(const float4*)(h + i8 + 4);
        uint4 o;
        o.x = (u32)f2bf(a.x) | ((u32)f2bf(a.y) << 16);
        o.y = (u32)f2bf(a.z) | ((u32)f2bf(a.w) << 16);
        o.z = (u32)f2bf(b.x) | ((u32)f2bf(b.y) << 16);
        o.w = (u32)f2bf(b.z) | ((u32)f2bf(b.w) << 16);
        *(uint4*)(hb + i8) = o;
    } else if (gid < CVT_H_N + CVT_WG_N) {
        int g = gid - CVT_H_N;
        int k = g % DIN, n = (g / DIN) % DF, m = g / (DIN * DF);
        WgT[g] = f2bf(Wg[((size_t)m * DIN + k) * DF + n]);
    } else if (gid < CVT_H_N + CVT_WG_N + CVT_W1_N) {
        int g = gid - CVT_H_N - CVT_WG_N;
        int k = g % DF, n = g / DF;
        W1T[g] = f2bf(W1[(size_t)k * HID + n]);
    } else if (gid < CVT_H_N + CVT_WG_N + CVT_W1_N + CVT_WAL_N) {
        int g = gid - CVT_H_N - CVT_WG_N - CVT_W1_N;
        int k = g & (DIN - 1), c = (g >> 7) & 15, m = g >> 11;
        int hh = c & 7;
        const float* a  = (c < 8 ? al : ar) + ((size_t)m * NH + hh) * 32;
        const float* wg = Wg + ((size_t)m * DIN + k) * DF + 32 * hh;
        float s = 0.f;
#pragma unroll
        for (int d = 0; d < 32; d++) s += wg[d] * a[d];
        WALT[g] = f2bf(s);
    }
}

// ---------------------------------------------------------------------------
// 1) feat[m] = h @ W_gat[m] via MFMA 16x16x32 bf16; wave does 16x256 strip,
//    plus one extra col-block vs WALT producing el/er (fp32) in the epilogue.
// ---------------------------------------------------------------------------
__global__ __launch_bounds__(256) void k_gemm_feat(
    const u16* __restrict__ hb, const u16* __restrict__ WgT, const u16* __restrict__ WALT,
    u16* __restrict__ feat, float* __restrict__ el, float* __restrict__ er)
{
    const int tid = threadIdx.x, lane = tid & 63, wid = tid >> 6;
    const int quad = lane >> 4, l16 = lane & 15;
    const int m    = blockIdx.y;
    const int row0 = blockIdx.x * 64 + wid * 16;

    const int arow = row0 + l16;
    const int arc  = arow < NN ? arow : NN - 1;
    const u16* ab = hb + (size_t)arc * DIN + quad * 8;
    bf16x8 afrag[4];
#pragma unroll
    for (int ks = 0; ks < 4; ks++) afrag[ks] = *(const bf16x8*)(ab + ks * 32);

    const u16* bb0 = WgT + ((size_t)m * DF + l16) * DIN + quad * 8;
    f32x4 acc[16];
#pragma unroll
    for (int nt = 0; nt < 16; nt++) { acc[nt][0]=0.f; acc[nt][1]=0.f; acc[nt][2]=0.f; acc[nt][3]=0.f; }

#pragma unroll
    for (int nt = 0; nt < 16; nt++) {
        const u16* bb = bb0 + (size_t)nt * 16 * DIN;
#pragma unroll
        for (int ks = 0; ks < 4; ks++) {
            bf16x8 bfrag = *(const bf16x8*)(bb + ks * 32);
            acc[nt] = __builtin_amdgcn_mfma_f32_16x16x32_bf16(afrag[ks], bfrag, acc[nt], 0, 0, 0);
        }
    }
    // extra col-block: el/er
    f32x4 acce; acce[0]=0.f; acce[1]=0.f; acce[2]=0.f; acce[3]=0.f;
    {
        const u16* eb = WALT + ((size_t)m * 16 + l16) * DIN + quad * 8;
#pragma unroll
        for (int ks = 0; ks < 4; ks++) {
            bf16x8 bfrag = *(const bf16x8*)(eb + ks * 32);
            acce = __builtin_amdgcn_mfma_f32_16x16x32_bf16(afrag[ks], bfrag, acce, 0, 0, 0);
        }
    }
    const int rbase = row0 + quad * 4;
#pragma unroll
    for (int nt = 0; nt < 16; nt++)
#pragma unroll
        for (int r = 0; r < 4; r++) {
            int gr = rbase + r;
            if (gr < NN)
                feat[((size_t)m * NN + gr) * DF + nt * 16 + l16] = f2bf(acc[nt][r]);
        }
#pragma unroll
    for (int r = 0; r < 4; r++) {
        int gr = rbase + r;
        if (gr < NN) {
            if (l16 < 8) el[((size_t)m * NN + gr) * NH + l16]       = acce[r];
            else         er[((size_t)m * NN + gr) * NH + (l16 - 8)] = acce[r];
        }
    }
}

// ---------------------------------------------------------------------------
// 3) CSR build: count, 3-kernel exclusive scan, cursor-atomic scatter.
// ---------------------------------------------------------------------------
__global__ void k_count(const int* __restrict__ dst, int* __restrict__ counts) {
    int e = blockIdx.x * 256 + threadIdx.x, m = blockIdx.y;
    if (e < NE) atomicAdd(&counts[m * NN + dst[(size_t)m * NE + e]], 1);
}

__global__ void k_scan_a(const int* __restrict__ counts, int* __restrict__ rs, int* __restrict__ bsum) {
    __shared__ int s[256];
    int tid = threadIdx.x, g = blockIdx.x * 256 + tid;
    int v = (g < NC) ? counts[g] : 0;
    s[tid] = v; __syncthreads();
    for (int off = 1; off < 256; off <<= 1) {
        int u = (tid >= off) ? s[tid - off] : 0;
        __syncthreads();
        s[tid] += u;
        __syncthreads();
    }
    if (g < NC) rs[g] = s[tid] - v;
    if (tid == 255) bsum[blockIdx.x] = s[255];
}

__global__ void k_scan_b(const int* __restrict__ bsum, int* __restrict__ boff) {
    __shared__ int s[1024];
    int tid = threadIdx.x;
    int v = (tid < SCAN_NB) ? bsum[tid] : 0;
    s[tid] = v; __syncthreads();
    for (int off = 1; off < 1024; off <<= 1) {
        int u = (tid >= off) ? s[tid - off] : 0;
        __syncthreads();
        s[tid] += u;
        __syncthreads();
    }
    if (tid < SCAN_NB) boff[tid] = s[tid] - v;
}

__global__ void k_scan_c(int* __restrict__ rs, const int* __restrict__ boff) {
    int g = blockIdx.x * 256 + threadIdx.x;
    if (g < NC) rs[g] += boff[blockIdx.x];
}

__global__ void k_scatter(const int* __restrict__ src, const int* __restrict__ dst,
                          const int* __restrict__ rs, int* __restrict__ cursor,
                          int* __restrict__ src_csr) {
    int e = blockIdx.x * 256 + threadIdx.x, m = blockIdx.y;
    if (e >= NE) return;
    int idx = m * NN + dst[(size_t)m * NE + e];
    int pos = rs[idx] + atomicAdd(&cursor[idx], 1);
    src_csr[pos] = src[(size_t)m * NE + e];
}

// ---------------------------------------------------------------------------
// 4) Destination-centric GAT, single pass, 8-way batched gathers (16 loads
//    in flight/wave), packed float2 accumulation, fmaxf-leaky.
// ---------------------------------------------------------------------------
__global__ __launch_bounds__(256) void k_node(
    const int* __restrict__ src_csr, const int* __restrict__ rs, const int* __restrict__ counts,
    const float* __restrict__ el, const float* __restrict__ er,
    const u16* __restrict__ feat, const float* __restrict__ bias, u16* __restrict__ z)
{
    const int lane = threadIdx.x & 63, wid = threadIdx.x >> 6;
    const int t = blockIdx.x * 4 + wid, m = blockIdx.y;
    if (t >= NN) return;
    const int idx  = m * NN + t;
    const int row0 = rs[idx];
    const int deg  = counts[idx];
    const int kl   = lane >> 3;
    const int l4   = lane * 4;

    const float erm  = er[idx * NH + kl];
    const float* elm = el + m * NN * NH;
    const u16*   fm  = feat + m * NN * DF;
    const int*   cs  = src_csr + row0;

    float sm = 0.f;
    f32x2 A01; A01.x = 0.f; A01.y = 0.f;
    f32x2 A23; A23.x = 0.f; A23.y = 0.f;

    int j = 0;
    for (; j + 8 <= deg; j += 8) {
        int   sv[8];
        float xv[8];
        uint2 uv[8];
#pragma unroll
        for (int i = 0; i < 8; i++) sv[i] = cs[j + i];
#pragma unroll
        for (int i = 0; i < 8; i++) xv[i] = elm[sv[i] * NH + kl];
#pragma unroll
        for (int i = 0; i < 8; i++) uv[i] = *(const uint2*)(fm + sv[i] * DF + l4);
#pragma unroll
        for (int i = 0; i < 8; i++) {
            float x = xv[i] + erm;
            x = fmaxf(x, 0.2f * x);
            float w = __expf(x);
            sm += w;
            f32x2 wv; wv.x = w; wv.y = w;
            A01 += wv * bfp(uv[i].x);
            A23 += wv * bfp(uv[i].y);
        }
    }
    for (; j + 4 <= deg; j += 4) {
        int   sv[4];
        float xv[4];
        uint2 uv[4];
#pragma unroll
        for (int i = 0; i < 4; i++) sv[i] = cs[j + i];
#pragma unroll
        for (int i = 0; i < 4; i++) xv[i] = elm[sv[i] * NH + kl];
#pragma unroll
        for (int i = 0; i < 4; i++) uv[i] = *(const uint2*)(fm + sv[i] * DF + l4);
#pragma unroll
        for (int i = 0; i < 4; i++) {
            float x = xv[i] + erm;
            x = fmaxf(x, 0.2f * x);
            float w = __expf(x);
            sm += w;
            f32x2 wv; wv.x = w; wv.y = w;
            A01 += wv * bfp(uv[i].x);
            A23 += wv * bfp(uv[i].y);
        }
    }
    for (; j < deg; ++j) {
        int s = cs[j];
        float x = elm[s * NH + kl] + erm;
        x = fmaxf(x, 0.2f * x);
        float w = __expf(x);
        sm += w;
        uint2 u = *(const uint2*)(fm + s * DF + l4);
        f32x2 wv; wv.x = w; wv.y = w;
        A01 += wv * bfp(u.x);
        A23 += wv * bfp(u.y);
    }
    const float rdm = 1.f / (sm + 1e-9f);

    float4 ub = *(const float4*)(bias + m * DF + l4);
    float z0 = A01.x * rdm + ub.x, z1 = A01.y * rdm + ub.y;
    float z2 = A23.x * rdm + ub.z, z3 = A23.y * rdm + ub.w;
    z0 = z0 > 0.f ? z0 : __expf(z0) - 1.f;
    z1 = z1 > 0.f ? z1 : __expf(z1) - 1.f;
    z2 = z2 > 0.f ? z2 : __expf(z2) - 1.f;
    z3 = z3 > 0.f ? z3 : __expf(z3) - 1.f;
    uint2 o;
    o.x = (u32)f2bf(z0) | ((u32)f2bf(z1) << 16);
    o.y = (u32)f2bf(z2) | ((u32)f2bf(z3) << 16);
    *(uint2*)(z + ((size_t)m * NN + t) * DF + l4) = o;
}

// ---------------------------------------------------------------------------
// 5) Semantic attention logits via MFMA, fused fast-tanh/w2/reduce epilogue.
// ---------------------------------------------------------------------------
__global__ __launch_bounds__(256) void k_sem(
    const u16* __restrict__ z, const u16* __restrict__ W1T,
    const float* __restrict__ b1, const float* __restrict__ w2,
    float* __restrict__ w_acc)
{
    __shared__ float buck[MP];
    const int tid = threadIdx.x, lane = tid & 63, wid = tid >> 6;
    const int quad = lane >> 4, l16 = lane & 15;
    if (tid < MP) buck[tid] = 0.f;
    __syncthreads();

    const int row0 = blockIdx.x * 64 + wid * 16;
    const int arow = row0 + l16;
    const int arc  = arow < NC ? arow : NC - 1;
    const u16* ab = z + (size_t)arc * DF + quad * 8;
    bf16x8 afrag[8];
#pragma unroll
    for (int ks = 0; ks < 8; ks++) afrag[ks] = *(const bf16x8*)(ab + ks * 32);

    const u16* bb0 = W1T + (size_t)l16 * DF + quad * 8;
    float rsum[4] = {0.f, 0.f, 0.f, 0.f};
#pragma unroll
    for (int nt = 0; nt < 8; nt++) {
        f32x4 acc; acc[0]=0.f; acc[1]=0.f; acc[2]=0.f; acc[3]=0.f;
        const u16* bb = bb0 + (size_t)nt * 16 * DF;
#pragma unroll
        for (int ks = 0; ks < 8; ks++) {
            bf16x8 bfrag = *(const bf16x8*)(bb + ks * 32);
            acc = __builtin_amdgcn_mfma_f32_16x16x32_bf16(afrag[ks], bfrag, acc, 0, 0, 0);
        }
        const int col = nt * 16 + l16;
        const float bb1 = b1[col], ww2 = w2[col];
#pragma unroll
        for (int r = 0; r < 4; r++) rsum[r] += tanh_fast(acc[r] + bb1) * ww2;
    }
#pragma unroll
    for (int msk = 1; msk <= 8; msk <<= 1)
#pragma unroll
        for (int r = 0; r < 4; r++) rsum[r] += __shfl_xor(rsum[r], msk);

    if (l16 == 0) {
#pragma unroll
        for (int r = 0; r < 4; r++) {
            int g = row0 + quad * 4 + r;
            if (g < NC) atomicAdd(&buck[g / NN], rsum[r]);
        }
    }
    __syncthreads();
    if (tid < MP) atomicAdd(w_acc + tid, buck[tid]);
}

__global__ void k_beta(const float* __restrict__ w_acc, float* __restrict__ beta) {
    if (threadIdx.x == 0 && blockIdx.x == 0) {
        float w0 = w_acc[0] / (float)NN, w1 = w_acc[1] / (float)NN, w2 = w_acc[2] / (float)NN;
        float mx = fmaxf(w0, fmaxf(w1, w2));
        float e0 = expf(w0 - mx), e1 = expf(w1 - mx), e2 = expf(w2 - mx);
        float s = e0 + e1 + e2;
        beta[0] = e0 / s; beta[1] = e1 / s; beta[2] = e2 / s;
    }
}

__global__ __launch_bounds__(256) void k_combine(
    const u16* __restrict__ z, const float* __restrict__ beta, float* __restrict__ out)
{
    size_t i = ((size_t)blockIdx.x * 256 + threadIdx.x) * 8;
    if (i >= (size_t)NN * DF) return;
    float b0 = beta[0], b1 = beta[1], b2 = beta[2];
    uint4 u0 = *(const uint4*)(z + i);
    uint4 u1 = *(const uint4*)(z + (size_t)NN * DF + i);
    uint4 u2 = *(const uint4*)(z + 2 * (size_t)NN * DF + i);
    float4 oa, ob;
    oa.x = b0 * bf2f((u16)(u0.x & 0xffff)) + b1 * bf2f((u16)(u1.x & 0xffff)) + b2 * bf2f((u16)(u2.x & 0xffff));
    oa.y = b0 * bf2f((u16)(u0.x >> 16))    + b1 * bf2f((u16)(u1.x >> 16))    + b2 * bf2f((u16)(u2.x >> 16));
    oa.z = b0 * bf2f((u16)(u0.y & 0xffff)) + b1 * bf2f((u16)(u1.y & 0xffff)) + b2 * bf2f((u16)(u2.y & 0xffff));
    oa.w = b0 * bf2f((u16)(u0.y >> 16))    + b1 * bf2f((u16)(u1.y >> 16))    + b2 * bf2f((u16)(u2.y >> 16));
    ob.x = b0 * bf2f((u16)(u0.z & 0xffff)) + b1 * bf2f((u16)(u1.z & 0xffff)) + b2 * bf2f((u16)(u2.z & 0xffff));
    ob.y = b0 * bf2f((u16)(u0.z >> 16))    + b1 * bf2f((u16)(u1.z >> 16))    + b2 * bf2f((u16)(u2.z >> 16));
    ob.z = b0 * bf2f((u16)(u0.w & 0xffff)) + b1 * bf2f((u16)(u1.w & 0xffff)) + b2 * bf2f((u16)(u2.w & 0xffff));
    ob.w = b0 * bf2f((u16)(u0.w >> 16))    + b1 * bf2f((u16)(u1.w >> 16))    + b2 * bf2f((u16)(u2.w >> 16));
    *(float4*)(out + i) = oa;
    *(float4*)(out + i + 4) = ob;
}

// ---------------------------------------------------------------------------
extern "C" void kernel_launch(void* const* d_in, const int* in_sizes, int n_in,
                              void* d_out, int out_size, void* d_ws, size_t ws_size,
                              hipStream_t stream)
{
    const float* h    = (const float*)d_in[0];
    const float* Wg   = (const float*)d_in[1];
    const float* al   = (const float*)d_in[2];
    const float* ar   = (const float*)d_in[3];
    const float* bias = (const float*)d_in[4];
    const float* W1   = (const float*)d_in[5];
    const float* b1   = (const float*)d_in[6];
    const float* w2   = (const float*)d_in[7];
    const int*   src  = (const int*)d_in[8];
    const int*   dst  = (const int*)d_in[9];
    float* out = (float*)d_out;

    char* w = (char*)d_ws;
    size_t off = 0;
    auto take = [&](size_t b) -> char* {
        char* p = w + off;
        off = (off + b + 255) & ~(size_t)255;
        return p;
    };
    u16*   feat    = (u16*)  take((size_t)MP * NN * DF * 2);
    u16*   zbuf    = (u16*)  take((size_t)MP * NN * DF * 2);
    u16*   hb      = (u16*)  take((size_t)NN * DIN * 2);
    u16*   WgT     = (u16*)  take((size_t)MP * DF * DIN * 2);
    u16*   W1T     = (u16*)  take((size_t)HID * DF * 2);
    u16*   WALT    = (u16*)  take((size_t)MP * 16 * DIN * 2);
    float* el      = (float*)take((size_t)MP * NN * NH * 4);
    float* er      = (float*)take((size_t)MP * NN * NH * 4);
    int*   counts  = (int*)  take((size_t)NC * 4);
    int*   rowst   = (int*)  take((size_t)NC * 4);
    int*   cursor  = (int*)  take((size_t)NC * 4);
    int*   src_csr = (int*)  take((size_t)MP * NE * 4);
    int*   bsum    = (int*)  take(1024 * 4);
    int*   boff    = (int*)  take(1024 * 4);
    float* w_acc   = (float*)take(64);
    float* beta    = (float*)take(64);

    hipMemsetAsync(counts, 0, (size_t)NC * 4, stream);
    hipMemsetAsync(cursor, 0, (size_t)NC * 4, stream);
    hipMemsetAsync(w_acc, 0, 64, stream);

    k_cvt_all<<<(CVT_H_N + CVT_WG_N + CVT_W1_N + CVT_WAL_N + 255) / 256, 256, 0, stream>>>(
        h, Wg, W1, al, ar, hb, WgT, W1T, WALT);

    k_gemm_feat<<<dim3((NN + 63) / 64, MP), 256, 0, stream>>>(hb, WgT, WALT, feat, el, er);
    k_count<<<dim3((NE + 255) / 256, MP), 256, 0, stream>>>(dst, counts);
    k_scan_a<<<SCAN_NB, 256, 0, stream>>>(counts, rowst, bsum);
    k_scan_b<<<1, 1024, 0, stream>>>(bsum, boff);
    k_scan_c<<<SCAN_NB, 256, 0, stream>>>(rowst, boff);
    k_scatter<<<dim3((NE + 255) / 256, MP), 256, 0, stream>>>(src, dst, rowst, cursor, src_csr);
    k_node<<<dim3((NN + 3) / 4, MP), 256, 0, stream>>>(src_csr, rowst, counts, el, er, feat, bias, zbuf);
    k_sem<<<(NC + 63) / 64, 256, 0, stream>>>(zbuf, W1T, b1, w2, w_acc);
    k_beta<<<1, 64, 0, stream>>>(w_acc, beta);
    k_combine<<<(NN * DF / 8 + 255) / 256, 256, 0, stream>>>(zbuf, beta, out);
}

// Round 10
// 663.119 us; speedup vs baseline: 1.0979x; 1.0979x over previous
//
#include <hip/hip_runtime.h>
#include <hip/hip_bf16.h>

#define NN   50000
#define NE   800000
#define MP   3
#define DIN  128
#define DF   256     // HEADS*OUT_DIM
#define NH   8
#define HID  128
#define NC   (MP*NN)              // 150000
#define SCAN_NB ((NC + 255)/256)  // 586

typedef unsigned short u16;
typedef unsigned int   u32;
typedef __attribute__((ext_vector_type(8))) short bf16x8;   // MFMA A/B frag
typedef __attribute__((ext_vector_type(4))) float f32x4;    // MFMA C/D frag
typedef __attribute__((ext_vector_type(2))) float f32x2;    // pk-math pair

__device__ __forceinline__ float bf2f(u16 u) {
    return __uint_as_float(((u32)u) << 16);
}
__device__ __forceinline__ u16 f2bf(float f) {
    u32 x = __float_as_uint(f);
    u32 r = x + 0x7fffu + ((x >> 16) & 1u);   // round-to-nearest-even
    return (u16)(r >> 16);
}
__device__ __forceinline__ f32x2 bfp(u32 u) {   // unpack bf16 pair -> f32x2
    f32x2 r;
    r.x = __uint_as_float(u << 16);
    r.y = __uint_as_float(u & 0xffff0000u);
    return r;
}
__device__ __forceinline__ float tanh_fast(float x) {
    float c = fminf(fmaxf(x, -15.f), 15.f);
    float t = __expf(2.f * c);
    return (t - 1.f) / (t + 1.f);
}

// ---------------------------------------------------------------------------
// 0) fused: converts (h->hb, Wg->WgT, W1->W1T, WAL) + edge count w/ rank.
//    cvt blocks [0, CVT_NB); count blocks [CVT_NB, CVT_NB + 3*CNT_NB).
// ---------------------------------------------------------------------------
#define CVT_H_N   (NN * DIN / 8)          // 800000
#define CVT_WG_N  (MP * DF * DIN)         // 98304
#define CVT_W1_N  (HID * DF)              // 32768
#define CVT_WAL_N (MP * 16 * DIN)         // 6144
#define CVT_TOT_N (CVT_H_N + CVT_WG_N + CVT_W1_N + CVT_WAL_N)   // 937216
#define CVT_NB    ((CVT_TOT_N + 255) / 256)                     // 3661
#define CNT_NB    ((NE + 255) / 256)                            // 3125
__global__ __launch_bounds__(256) void k_cvt_count(
    const float* __restrict__ h, const float* __restrict__ Wg, const float* __restrict__ W1,
    const float* __restrict__ al, const float* __restrict__ ar,
    u16* __restrict__ hb, u16* __restrict__ WgT, u16* __restrict__ W1T, u16* __restrict__ WALT,
    const int* __restrict__ dst, int* __restrict__ counts, int* __restrict__ rank)
{
    if (blockIdx.x >= CVT_NB) {           // edge-count path
        int b = blockIdx.x - CVT_NB;
        int m = b / CNT_NB;
        int e = (b - m * CNT_NB) * 256 + threadIdx.x;
        if (e < NE) {
            int idx = m * NN + dst[(size_t)m * NE + e];
            rank[(size_t)m * NE + e] = atomicAdd(&counts[idx], 1);
        }
        return;
    }
    int gid = blockIdx.x * 256 + threadIdx.x;
    if (gid < CVT_H_N) {
        size_t i8 = (size_t)gid * 8;
        float4 a = *(const float4*)(h + i8);
        float4 b = *(const float4*)(h + i8 + 4);
        uint4 o;
        o.x = (u32)f2bf(a.x) | ((u32)f2bf(a.y) << 16);
        o.y = (u32)f2bf(a.z) | ((u32)f2bf(a.w) << 16);
        o.z = (u32)f2bf(b.x) | ((u32)f2bf(b.y) << 16);
        o.w = (u32)f2bf(b.z) | ((u32)f2bf(b.w) << 16);
        *(uint4*)(hb + i8) = o;
    } else if (gid < CVT_H_N + CVT_WG_N) {
        int g = gid - CVT_H_N;
        int k = g % DIN, n = (g / DIN) % DF, m = g / (DIN * DF);
        WgT[g] = f2bf(Wg[((size_t)m * DIN + k) * DF + n]);
    } else if (gid < CVT_H_N + CVT_WG_N + CVT_W1_N) {
        int g = gid - CVT_H_N - CVT_WG_N;
        int k = g % DF, n = g / DF;
        W1T[g] = f2bf(W1[(size_t)k * HID + n]);
    } else if (gid < CVT_TOT_N) {
        int g = gid - CVT_H_N - CVT_WG_N - CVT_W1_N;
        int k = g & (DIN - 1), c = (g >> 7) & 15, m = g >> 11;
        int hh = c & 7;
        const float* a  = (c < 8 ? al : ar) + ((size_t)m * NH + hh) * 32;
        const float* wg = Wg + ((size_t)m * DIN + k) * DF + 32 * hh;
        float s = 0.f;
#pragma unroll
        for (int d = 0; d < 32; d++) s += wg[d] * a[d];
        WALT[g] = f2bf(s);
    }
}

// ---------------------------------------------------------------------------
// 1) feat[m] = h @ W_gat[m] via MFMA 16x16x32 bf16; wave does 16x256 strip,
//    plus one extra col-block vs WALT producing el/er (fp32) in the epilogue.
// ---------------------------------------------------------------------------
__global__ __launch_bounds__(256) void k_gemm_feat(
    const u16* __restrict__ hb, const u16* __restrict__ WgT, const u16* __restrict__ WALT,
    u16* __restrict__ feat, float* __restrict__ el, float* __restrict__ er)
{
    const int tid = threadIdx.x, lane = tid & 63, wid = tid >> 6;
    const int quad = lane >> 4, l16 = lane & 15;
    const int m    = blockIdx.y;
    const int row0 = blockIdx.x * 64 + wid * 16;

    const int arow = row0 + l16;
    const int arc  = arow < NN ? arow : NN - 1;
    const u16* ab = hb + (size_t)arc * DIN + quad * 8;
    bf16x8 afrag[4];
#pragma unroll
    for (int ks = 0; ks < 4; ks++) afrag[ks] = *(const bf16x8*)(ab + ks * 32);

    const u16* bb0 = WgT + ((size_t)m * DF + l16) * DIN + quad * 8;
    f32x4 acc[16];
#pragma unroll
    for (int nt = 0; nt < 16; nt++) { acc[nt][0]=0.f; acc[nt][1]=0.f; acc[nt][2]=0.f; acc[nt][3]=0.f; }

#pragma unroll
    for (int nt = 0; nt < 16; nt++) {
        const u16* bb = bb0 + (size_t)nt * 16 * DIN;
#pragma unroll
        for (int ks = 0; ks < 4; ks++) {
            bf16x8 bfrag = *(const bf16x8*)(bb + ks * 32);
            acc[nt] = __builtin_amdgcn_mfma_f32_16x16x32_bf16(afrag[ks], bfrag, acc[nt], 0, 0, 0);
        }
    }
    // extra col-block: el/er
    f32x4 acce; acce[0]=0.f; acce[1]=0.f; acce[2]=0.f; acce[3]=0.f;
    {
        const u16* eb = WALT + ((size_t)m * 16 + l16) * DIN + quad * 8;
#pragma unroll
        for (int ks = 0; ks < 4; ks++) {
            bf16x8 bfrag = *(const bf16x8*)(eb + ks * 32);
            acce = __builtin_amdgcn_mfma_f32_16x16x32_bf16(afrag[ks], bfrag, acce, 0, 0, 0);
        }
    }
    const int rbase = row0 + quad * 4;
#pragma unroll
    for (int nt = 0; nt < 16; nt++)
#pragma unroll
        for (int r = 0; r < 4; r++) {
            int gr = rbase + r;
            if (gr < NN)
                feat[((size_t)m * NN + gr) * DF + nt * 16 + l16] = f2bf(acc[nt][r]);
        }
#pragma unroll
    for (int r = 0; r < 4; r++) {
        int gr = rbase + r;
        if (gr < NN) {
            if (l16 < 8) el[((size_t)m * NN + gr) * NH + l16]       = acce[r];
            else         er[((size_t)m * NN + gr) * NH + (l16 - 8)] = acce[r];
        }
    }
}

// ---------------------------------------------------------------------------
// 3) scan (2 kernels; boff add folded into consumers) + rank-based scatter.
// ---------------------------------------------------------------------------
__global__ void k_scan_a(const int* __restrict__ counts, int* __restrict__ rs, int* __restrict__ bsum) {
    __shared__ int s[256];
    int tid = threadIdx.x, g = blockIdx.x * 256 + tid;
    int v = (g < NC) ? counts[g] : 0;
    s[tid] = v; __syncthreads();
    for (int off = 1; off < 256; off <<= 1) {
        int u = (tid >= off) ? s[tid - off] : 0;
        __syncthreads();
        s[tid] += u;
        __syncthreads();
    }
    if (g < NC) rs[g] = s[tid] - v;
    if (tid == 255) bsum[blockIdx.x] = s[255];
}

__global__ void k_scan_b(const int* __restrict__ bsum, int* __restrict__ boff) {
    __shared__ int s[1024];
    int tid = threadIdx.x;
    int v = (tid < SCAN_NB) ? bsum[tid] : 0;
    s[tid] = v; __syncthreads();
    for (int off = 1; off < 1024; off <<= 1) {
        int u = (tid >= off) ? s[tid - off] : 0;
        __syncthreads();
        s[tid] += u;
        __syncthreads();
    }
    if (tid < SCAN_NB) boff[tid] = s[tid] - v;
}

__global__ void k_scatter(const int* __restrict__ src, const int* __restrict__ dst,
                          const int* __restrict__ rs, const int* __restrict__ boff,
                          const int* __restrict__ rank, int* __restrict__ src_csr) {
    int e = blockIdx.x * 256 + threadIdx.x, m = blockIdx.y;
    if (e >= NE) return;
    int idx = m * NN + dst[(size_t)m * NE + e];
    int pos = rs[idx] + boff[idx >> 8] + rank[(size_t)m * NE + e];
    src_csr[pos] = src[(size_t)m * NE + e];
}

// ---------------------------------------------------------------------------
// 4) Destination-centric GAT, single pass, 4-way batched gathers, packed
//    float2 accumulation (v_pk_fma_f32), fmaxf-leaky.
// ---------------------------------------------------------------------------
__global__ __launch_bounds__(256) void k_node(
    const int* __restrict__ src_csr, const int* __restrict__ rs, const int* __restrict__ boff,
    const int* __restrict__ counts,
    const float* __restrict__ el, const float* __restrict__ er,
    const u16* __restrict__ feat, const float* __restrict__ bias, u16* __restrict__ z)
{
    const int lane = threadIdx.x & 63, wid = threadIdx.x >> 6;
    const int t = blockIdx.x * 4 + wid, m = blockIdx.y;
    if (t >= NN) return;
    const int idx  = m * NN + t;
    const int row0 = rs[idx] + boff[idx >> 8];
    const int deg  = counts[idx];
    const int kl   = lane >> 3;
    const int l4   = lane * 4;

    const float erm  = er[idx * NH + kl];
    const float* elm = el + m * NN * NH;
    const u16*   fm  = feat + m * NN * DF;
    const int*   cs  = src_csr + row0;

    float sm = 0.f;
    f32x2 A01; A01.x = 0.f; A01.y = 0.f;
    f32x2 A23; A23.x = 0.f; A23.y = 0.f;

    int j = 0;
    for (; j + 4 <= deg; j += 4) {
        int s0 = cs[j], s1 = cs[j + 1], s2 = cs[j + 2], s3 = cs[j + 3];
        float x0 = elm[s0 * NH + kl];
        float x1 = elm[s1 * NH + kl];
        float x2 = elm[s2 * NH + kl];
        float x3 = elm[s3 * NH + kl];
        uint2 u0 = *(const uint2*)(fm + s0 * DF + l4);
        uint2 u1 = *(const uint2*)(fm + s1 * DF + l4);
        uint2 u2 = *(const uint2*)(fm + s2 * DF + l4);
        uint2 u3 = *(const uint2*)(fm + s3 * DF + l4);
        float t0 = x0 + erm; t0 = fmaxf(t0, 0.2f * t0); float w0 = __expf(t0);
        float t1 = x1 + erm; t1 = fmaxf(t1, 0.2f * t1); float w1 = __expf(t1);
        float t2 = x2 + erm; t2 = fmaxf(t2, 0.2f * t2); float w2 = __expf(t2);
        float t3 = x3 + erm; t3 = fmaxf(t3, 0.2f * t3); float w3 = __expf(t3);
        sm += (w0 + w1) + (w2 + w3);
        f32x2 wv;
        wv.x = w0; wv.y = w0; A01 += wv * bfp(u0.x); A23 += wv * bfp(u0.y);
        wv.x = w1; wv.y = w1; A01 += wv * bfp(u1.x); A23 += wv * bfp(u1.y);
        wv.x = w2; wv.y = w2; A01 += wv * bfp(u2.x); A23 += wv * bfp(u2.y);
        wv.x = w3; wv.y = w3; A01 += wv * bfp(u3.x); A23 += wv * bfp(u3.y);
    }
    for (; j < deg; ++j) {
        int s = cs[j];
        float x = elm[s * NH + kl] + erm;
        x = fmaxf(x, 0.2f * x);
        float w = __expf(x);
        sm += w;
        uint2 u = *(const uint2*)(fm + s * DF + l4);
        f32x2 wv; wv.x = w; wv.y = w;
        A01 += wv * bfp(u.x);
        A23 += wv * bfp(u.y);
    }
    const float rdm = 1.f / (sm + 1e-9f);

    float4 ub = *(const float4*)(bias + m * DF + l4);
    float z0 = A01.x * rdm + ub.x, z1 = A01.y * rdm + ub.y;
    float z2 = A23.x * rdm + ub.z, z3 = A23.y * rdm + ub.w;
    z0 = z0 > 0.f ? z0 : __expf(z0) - 1.f;
    z1 = z1 > 0.f ? z1 : __expf(z1) - 1.f;
    z2 = z2 > 0.f ? z2 : __expf(z2) - 1.f;
    z3 = z3 > 0.f ? z3 : __expf(z3) - 1.f;
    uint2 o;
    o.x = (u32)f2bf(z0) | ((u32)f2bf(z1) << 16);
    o.y = (u32)f2bf(z2) | ((u32)f2bf(z3) << 16);
    *(uint2*)(z + ((size_t)m * NN + t) * DF + l4) = o;
}

// ---------------------------------------------------------------------------
// 5) Semantic attention logits via MFMA, fused fast-tanh/w2/reduce epilogue.
// ---------------------------------------------------------------------------
__global__ __launch_bounds__(256) void k_sem(
    const u16* __restrict__ z, const u16* __restrict__ W1T,
    const float* __restrict__ b1, const float* __restrict__ w2,
    float* __restrict__ w_acc)
{
    __shared__ float buck[MP];
    const int tid = threadIdx.x, lane = tid & 63, wid = tid >> 6;
    const int quad = lane >> 4, l16 = lane & 15;
    if (tid < MP) buck[tid] = 0.f;
    __syncthreads();

    const int row0 = blockIdx.x * 64 + wid * 16;
    const int arow = row0 + l16;
    const int arc  = arow < NC ? arow : NC - 1;
    const u16* ab = z + (size_t)arc * DF + quad * 8;
    bf16x8 afrag[8];
#pragma unroll
    for (int ks = 0; ks < 8; ks++) afrag[ks] = *(const bf16x8*)(ab + ks * 32);

    const u16* bb0 = W1T + (size_t)l16 * DF + quad * 8;
    float rsum[4] = {0.f, 0.f, 0.f, 0.f};
#pragma unroll
    for (int nt = 0; nt < 8; nt++) {
        f32x4 acc; acc[0]=0.f; acc[1]=0.f; acc[2]=0.f; acc[3]=0.f;
        const u16* bb = bb0 + (size_t)nt * 16 * DF;
#pragma unroll
        for (int ks = 0; ks < 8; ks++) {
            bf16x8 bfrag = *(const bf16x8*)(bb + ks * 32);
            acc = __builtin_amdgcn_mfma_f32_16x16x32_bf16(afrag[ks], bfrag, acc, 0, 0, 0);
        }
        const int col = nt * 16 + l16;
        const float bb1 = b1[col], ww2 = w2[col];
#pragma unroll
        for (int r = 0; r < 4; r++) rsum[r] += tanh_fast(acc[r] + bb1) * ww2;
    }
#pragma unroll
    for (int msk = 1; msk <= 8; msk <<= 1)
#pragma unroll
        for (int r = 0; r < 4; r++) rsum[r] += __shfl_xor(rsum[r], msk);

    if (l16 == 0) {
#pragma unroll
        for (int r = 0; r < 4; r++) {
            int g = row0 + quad * 4 + r;
            if (g < NC) atomicAdd(&buck[g / NN], rsum[r]);
        }
    }
    __syncthreads();
    if (tid < MP) atomicAdd(w_acc + tid, buck[tid]);
}

__global__ void k_beta(const float* __restrict__ w_acc, float* __restrict__ beta) {
    if (threadIdx.x == 0 && blockIdx.x == 0) {
        float w0 = w_acc[0] / (float)NN, w1 = w_acc[1] / (float)NN, w2 = w_acc[2] / (float)NN;
        float mx = fmaxf(w0, fmaxf(w1, w2));
        float e0 = expf(w0 - mx), e1 = expf(w1 - mx), e2 = expf(w2 - mx);
        float s = e0 + e1 + e2;
        beta[0] = e0 / s; beta[1] = e1 / s; beta[2] = e2 / s;
    }
}

__global__ __launch_bounds__(256) void k_combine(
    const u16* __restrict__ z, const float* __restrict__ beta, float* __restrict__ out)
{
    size_t i = ((size_t)blockIdx.x * 256 + threadIdx.x) * 8;
    if (i >= (size_t)NN * DF) return;
    float b0 = beta[0], b1 = beta[1], b2 = beta[2];
    uint4 u0 = *(const uint4*)(z + i);
    uint4 u1 = *(const uint4*)(z + (size_t)NN * DF + i);
    uint4 u2 = *(const uint4*)(z + 2 * (size_t)NN * DF + i);
    float4 oa, ob;
    oa.x = b0 * bf2f((u16)(u0.x & 0xffff)) + b1 * bf2f((u16)(u1.x & 0xffff)) + b2 * bf2f((u16)(u2.x & 0xffff));
    oa.y = b0 * bf2f((u16)(u0.x >> 16))    + b1 * bf2f((u16)(u1.x >> 16))    + b2 * bf2f((u16)(u2.x >> 16));
    oa.z = b0 * bf2f((u16)(u0.y & 0xffff)) + b1 * bf2f((u16)(u1.y & 0xffff)) + b2 * bf2f((u16)(u2.y & 0xffff));
    oa.w = b0 * bf2f((u16)(u0.y >> 16))    + b1 * bf2f((u16)(u1.y >> 16))    + b2 * bf2f((u16)(u2.y >> 16));
    ob.x = b0 * bf2f((u16)(u0.z & 0xffff)) + b1 * bf2f((u16)(u1.z & 0xffff)) + b2 * bf2f((u16)(u2.z & 0xffff));
    ob.y = b0 * bf2f((u16)(u0.z >> 16))    + b1 * bf2f((u16)(u1.z >> 16))    + b2 * bf2f((u16)(u2.z >> 16));
    ob.z = b0 * bf2f((u16)(u0.w & 0xffff)) + b1 * bf2f((u16)(u1.w & 0xffff)) + b2 * bf2f((u16)(u2.w & 0xffff));
    ob.w = b0 * bf2f((u16)(u0.w >> 16))    + b1 * bf2f((u16)(u1.w >> 16))    + b2 * bf2f((u16)(u2.w >> 16));
    *(float4*)(out + i) = oa;
    *(float4*)(out + i + 4) = ob;
}

// ---------------------------------------------------------------------------
extern "C" void kernel_launch(void* const* d_in, const int* in_sizes, int n_in,
                              void* d_out, int out_size, void* d_ws, size_t ws_size,
                              hipStream_t stream)
{
    const float* h    = (const float*)d_in[0];
    const float* Wg   = (const float*)d_in[1];
    const float* al   = (const float*)d_in[2];
    const float* ar   = (const float*)d_in[3];
    const float* bias = (const float*)d_in[4];
    const float* W1   = (const float*)d_in[5];
    const float* b1   = (const float*)d_in[6];
    const float* w2   = (const float*)d_in[7];
    const int*   src  = (const int*)d_in[8];
    const int*   dst  = (const int*)d_in[9];
    float* out = (float*)d_out;

    char* w = (char*)d_ws;
    size_t off = 0;
    auto take = [&](size_t b) -> char* {
        char* p = w + off;
        off = (off + b + 255) & ~(size_t)255;
        return p;
    };
    u16*   feat    = (u16*)  take((size_t)MP * NN * DF * 2);
    u16*   zbuf    = (u16*)  take((size_t)MP * NN * DF * 2);
    u16*   hb      = (u16*)  take((size_t)NN * DIN * 2);
    u16*   WgT     = (u16*)  take((size_t)MP * DF * DIN * 2);
    u16*   W1T     = (u16*)  take((size_t)HID * DF * 2);
    u16*   WALT    = (u16*)  take((size_t)MP * 16 * DIN * 2);
    float* el      = (float*)take((size_t)MP * NN * NH * 4);
    float* er      = (float*)take((size_t)MP * NN * NH * 4);
    int*   counts  = (int*)  take((size_t)NC * 4);
    int*   rowst   = (int*)  take((size_t)NC * 4);
    int*   src_csr = (int*)  take((size_t)MP * NE * 4);
    int*   bsum    = (int*)  take(1024 * 4);
    int*   boff    = (int*)  take(1024 * 4);
    float* w_acc   = (float*)take(64);
    float* beta    = (float*)take(64);
    // rank is dead before k_node writes zbuf -> alias it onto zbuf
    int*   rank    = (int*)zbuf;

    hipMemsetAsync(counts, 0, (size_t)NC * 4, stream);
    hipMemsetAsync(w_acc, 0, 64, stream);

    k_cvt_count<<<CVT_NB + MP * CNT_NB, 256, 0, stream>>>(
        h, Wg, W1, al, ar, hb, WgT, W1T, WALT, dst, counts, rank);

    k_gemm_feat<<<dim3((NN + 63) / 64, MP), 256, 0, stream>>>(hb, WgT, WALT, feat, el, er);
    k_scan_a<<<SCAN_NB, 256, 0, stream>>>(counts, rowst, bsum);
    k_scan_b<<<1, 1024, 0, stream>>>(bsum, boff);
    k_scatter<<<dim3(CNT_NB, MP), 256, 0, stream>>>(src, dst, rowst, boff, rank, src_csr);
    k_node<<<dim3((NN + 3) / 4, MP), 256, 0, stream>>>(src_csr, rowst, boff, counts, el, er, feat, bias, zbuf);
    k_sem<<<(NC + 63) / 64, 256, 0, stream>>>(zbuf, W1T, b1, w2, w_acc);
    k_beta<<<1, 64, 0, stream>>>(w_acc, beta);
    k_combine<<<(NN * DF / 8 + 255) / 256, 256, 0, stream>>>(zbuf, beta, out);
}